// Round 4
// baseline (114.567 us; speedup 1.0000x reference)
//
#include <hip/hip_runtime.h>
#include <hip/hip_bf16.h>
#include <math.h>

// ProxyMLS: score = -0.5*(e2@iv^T - 2*e@(mu*iv)^T + const_j)
// pos_e = -32*(score-0.1) = 16*raw + (16*const_j + 3.2);  neg_e = 6.4 - pos_e
// R14: (1) k_main epilogue diet: per-column max computed on RAW acc via
// v_max3_f32 tree (pcv is column-constant so lmax = S2*rawmax + pcv), and
// neg-exp arg fused to a single FMA: arg = fma(-S2, acc, cn),
// cn = NEGC2 - pm - 2*pcv. ~40% fewer epilogue VALU ops.
// (2) k_red1+k_fin merged via last-block-done (threadfence + atomicAdd
// ticket, counter zeroed by k_prep each iteration); final phase prefetches
// all partials into registers and takes a log1p fast path (x<1e-7 -> x).
//
// Scale constants: S2 = 16*log2e, B2 = 3.2*log2e, NEGC2 = 6.4*log2e.
// Final converts back with m_natural = m' * ln2.

#define N_EMB 4096
#define C_CLS 8192
#define D_DIM 64
#define K_DIM 128   // concat [e^2 | e] x [iv | -2*mu*iv]
#define NCB 4       // cb tiles per k_main block

#define S2_F    23.083120654223414f   // 16  * log2(e)
#define B2_F     4.616624130844683f   // 3.2 * log2(e)
#define NEGC2_F  9.233248261689366f   // 6.4 * log2(e)
#define LN2_F    0.6931471805599453f

typedef __attribute__((ext_vector_type(8))) __bf16 bf16x8;
typedef __attribute__((ext_vector_type(4))) __bf16 bf16x4;
typedef __attribute__((ext_vector_type(16))) float f32x16;
typedef __attribute__((ext_vector_type(4))) int i32x4;

__device__ __forceinline__ void async_ld16(void* lds, const void* g) {
  __builtin_amdgcn_global_load_lds(
      (__attribute__((address_space(1))) void*)g,
      (__attribute__((address_space(3))) void*)lds, 16, 0, 0);
}

// Raw hardware exp2 (v_exp_f32). exp2f would call __ocml_exp2_f32
// (subnormal fixup, ~6-10 instrs) -- measured +3us in R12.
__device__ __forceinline__ float fexp2(float x) {
  float r;
  asm("v_exp_f32 %0, %1" : "=v"(r) : "v"(x));
  return r;
}

// 3-input max in one instruction (gfx9+).
__device__ __forceinline__ float fmax3(float a, float b, float c) {
  float r;
  asm("v_max3_f32 %0, %1, %2, %3" : "=v"(r) : "v"(a), "v"(b), "v"(c));
  return r;
}

// Vectorized prep: wave handles 4 rows; lane = (sub=lane>>4 row, q=lane&15
// covering d = q*4..q*4+3 via float4). A=[e^2|e], B=[iv|-2*mu*iv],
// const_j = sum_d(mu^2*iv + logvar) via 16-lane xor-shuffle reduce.
// Also zeroes the last-block ticket counter (workspace is re-poisoned
// between iterations).
__global__ void k_prep(const float* __restrict__ emb,
                       const float* __restrict__ mp,
                       const float* __restrict__ lvp,
                       __bf16* __restrict__ wsA,
                       __bf16* __restrict__ wsB,
                       float* __restrict__ constv,
                       int* __restrict__ counter) {
  if (blockIdx.x == 0 && threadIdx.x == 0) *counter = 0;
  const int wave = (int)((blockIdx.x * blockDim.x + threadIdx.x) >> 6);
  const int lane = threadIdx.x & 63;
  const int sub = lane >> 4, q = lane & 15;
  const int row = wave * 4 + sub;   // 12288 rows total
  if (row < N_EMB) {
    float4 e4 = *(const float4*)&emb[row * D_DIM + q * 4];
    bf16x4 sq = {(__bf16)(e4.x * e4.x), (__bf16)(e4.y * e4.y),
                 (__bf16)(e4.z * e4.z), (__bf16)(e4.w * e4.w)};
    bf16x4 ev = {(__bf16)e4.x, (__bf16)e4.y, (__bf16)e4.z, (__bf16)e4.w};
    *(bf16x4*)&wsA[row * K_DIM + q * 4] = sq;
    *(bf16x4*)&wsA[row * K_DIM + D_DIM + q * 4] = ev;
  } else {
    const int j = row - N_EMB;
    float4 mu4 = *(const float4*)&mp[j * D_DIM + q * 4];
    float4 lv4 = *(const float4*)&lvp[j * D_DIM + q * 4];
    float iv0 = __expf(-lv4.x), iv1 = __expf(-lv4.y);
    float iv2 = __expf(-lv4.z), iv3 = __expf(-lv4.w);
    bf16x4 ivv = {(__bf16)iv0, (__bf16)iv1, (__bf16)iv2, (__bf16)iv3};
    bf16x4 mv = {(__bf16)(-2.0f * mu4.x * iv0), (__bf16)(-2.0f * mu4.y * iv1),
                 (__bf16)(-2.0f * mu4.z * iv2), (__bf16)(-2.0f * mu4.w * iv3)};
    *(bf16x4*)&wsB[j * K_DIM + q * 4] = ivv;
    *(bf16x4*)&wsB[j * K_DIM + D_DIM + q * 4] = mv;
    float t = fmaf(mu4.x * mu4.x, iv0, lv4.x)
            + fmaf(mu4.y * mu4.y, iv1, lv4.y)
            + fmaf(mu4.z * mu4.z, iv2, lv4.z)
            + fmaf(mu4.w * mu4.w, iv3, lv4.w);
    #pragma unroll
    for (int s = 8; s >= 1; s >>= 1) t += __shfl_xor(t, s);  // within 16-group
    if (q == 0) constv[j] = t;
  }
}

// 128x(4x128) per block: A tile staged once, 4 B tiles staged sequentially
// (next tile's async loads fly under the current epilogue). bf16 32x32x16
// MFMA GEMM (K=128) + fused per-column online max / masked exp-sums (log2
// domain). Partials -> ws[rb][gcol].
//
// LDS tile layout: 128 rows x 16 chunks (16 B each), row stride 256 B.
// Slot (r, cs) holds GLOBAL chunk (r, cs ^ (r & 15)). Reader of chunk c of
// row r loads slot c ^ (r & 15) -> conflict-free (m136).
__global__ __launch_bounds__(256, 2) void k_main(
    const __bf16* __restrict__ wsA, const __bf16* __restrict__ wsB,
    const float* __restrict__ constv, const int* __restrict__ labels,
    float* __restrict__ wsM, float* __restrict__ wsP, float* __restrict__ wsN) {
  __shared__ __align__(16) char As[32768];  // 32 KB
  __shared__ __align__(16) char Bs[32768];  // 32 KB
  __shared__ float colred[2][128][3];       // 3 KB  (68.4 KB total -> 2 blk/CU)

  const int tid = threadIdx.x;
  const int rb  = blockIdx.x & 31;   // row block (N/128 = 32)
  const int cbg = blockIdx.x >> 5;   // col group (16 groups of NCB tiles)

  const char* Ag = (const char*)(wsA + (size_t)rb * 128 * K_DIM);
  const char* Bgb = (const char*)(wsB + (size_t)(cbg * NCB) * 128 * K_DIM);
  #pragma unroll
  for (int it = 0; it < 8; ++it) {
    int L = it * 256 + tid;
    int r = L >> 4, cs = L & 15;
    int goff = r * 256 + ((cs ^ (r & 15)) << 4);
    async_ld16(As + L * 16, Ag + goff);
  }
  #pragma unroll
  for (int it = 0; it < 8; ++it) {
    int L = it * 256 + tid;
    int r = L >> 4, cs = L & 15;
    int goff = r * 256 + ((cs ^ (r & 15)) << 4);
    async_ld16(Bs + L * 16, Bgb + goff);
  }

  const int wv = tid >> 6, lane = tid & 63;
  const int wr = wv >> 1, wc = wv & 1;   // 2x2 wave grid, 64x64 per wave
  const int l31 = lane & 31, kg = lane >> 5;  // A/B frag: row=l31, k=kg*8+j
  const int l15 = lane & 15;

  // Epilogue inputs straight to registers; latency hides under staging.
  // Label rows for C/D layout: base = wr*64 + mi*32 + 4*kg + 8*g.
  i32x4 labv[2][4];
  #pragma unroll
  for (int mi = 0; mi < 2; ++mi)
    #pragma unroll
    for (int g = 0; g < 4; ++g)
      labv[mi][g] = *(const i32x4*)&labels[rb * 128 + wr * 64 + mi * 32 +
                                           4 * kg + 8 * g];
  float cvv[NCB][2];
  #pragma unroll
  for (int cbi = 0; cbi < NCB; ++cbi)
    #pragma unroll
    for (int ni = 0; ni < 2; ++ni)
      cvv[cbi][ni] = constv[(cbg * NCB + cbi) * 128 + wc * 64 + ni * 32 + l31];

  __syncthreads();  // drains vmcnt: As + Bs(tile 0) ready

  #pragma unroll
  for (int cbi = 0; cbi < NCB; ++cbi) {
    const int cb = cbg * NCB + cbi;

    f32x16 acc[2][2];
    #pragma unroll
    for (int mi = 0; mi < 2; ++mi)
      #pragma unroll
      for (int ni = 0; ni < 2; ++ni)
        #pragma unroll
        for (int r = 0; r < 16; ++r) acc[mi][ni][r] = 0.f;

    #pragma unroll
    for (int kk = 0; kk < 8; ++kk) {       // K = 8 steps of 16
      const int c = kk * 2 + kg;           // wanted 16B K-chunk
      const int cofs = (c ^ l15) << 4;     // swizzled byte offset (row&15==l15)
      bf16x8 af[2], bfr[2];
      #pragma unroll
      for (int mi = 0; mi < 2; ++mi)
        af[mi] = *(const bf16x8*)(As + (wr * 64 + mi * 32 + l31) * 256 + cofs);
      #pragma unroll
      for (int ni = 0; ni < 2; ++ni)
        bfr[ni] = *(const bf16x8*)(Bs + (wc * 64 + ni * 32 + l31) * 256 + cofs);
      #pragma unroll
      for (int mi = 0; mi < 2; ++mi)
        #pragma unroll
        for (int ni = 0; ni < 2; ++ni)
          acc[mi][ni] = __builtin_amdgcn_mfma_f32_32x32x16_bf16(
              af[mi], bfr[ni], acc[mi][ni], 0, 0, 0);
    }

    __syncthreads();  // all waves done reading Bs

    if (cbi + 1 < NCB) {  // stage next B tile; flies under the epilogue
      const char* Bg = Bgb + (size_t)(cbi + 1) * 32768;
      #pragma unroll
      for (int it = 0; it < 8; ++it) {
        int L = it * 256 + tid;
        int r = L >> 4, cs = L & 15;
        int goff = r * 256 + ((cs ^ (r & 15)) << 4);
        async_ld16(Bs + L * 16, Bg + goff);
      }
    }

    // Epilogue. C/D layout (32x32, m74/m101): col = lane&31,
    // row = (reg&3) + 8*(reg>>2) + 4*kg.
    #pragma unroll
    for (int ni = 0; ni < 2; ++ni) {
      const int col_local = wc * 64 + ni * 32 + l31;
      const int gcol = cb * 128 + col_local;
      const float pcv = fmaf(S2_F, cvv[cbi][ni], B2_F);

      // Raw-acc max via v_max3 tree (pcv const per column, S2 > 0).
      #define AV(k) acc[(k) >> 4][ni][(k) & 15]
      float t0 = fmax3(AV(0), AV(1), AV(2));
      float t1 = fmax3(AV(3), AV(4), AV(5));
      float t2 = fmax3(AV(6), AV(7), AV(8));
      float t3 = fmax3(AV(9), AV(10), AV(11));
      float t4 = fmax3(AV(12), AV(13), AV(14));
      float t5 = fmax3(AV(15), AV(16), AV(17));
      float t6 = fmax3(AV(18), AV(19), AV(20));
      float t7 = fmax3(AV(21), AV(22), AV(23));
      float t8 = fmax3(AV(24), AV(25), AV(26));
      float t9 = fmax3(AV(27), AV(28), AV(29));
      float ta = fmaxf(AV(30), AV(31));
      #undef AV
      float u0 = fmax3(t0, t1, t2);
      float u1 = fmax3(t3, t4, t5);
      float u2 = fmax3(t6, t7, t8);
      float u3 = fmax3(t9, ta, u0);
      float rm = fmax3(u1, u2, u3);
      rm = fmaxf(rm, __shfl_xor(rm, 32));   // other kg half = other rows

      const float pm = S2_F * rm;
      const float lmax = pm + pcv;          // pe-domain column max
      const float cn = NEGC2_F - pm - 2.0f * pcv;  // neg arg = fma(-S2,a,cn)

      float nsa = 0.f, nsb = 0.f, ps = 0.f;
      #pragma unroll
      for (int mi = 0; mi < 2; ++mi)
        #pragma unroll
        for (int r = 0; r < 16; ++r) {
          float a = acc[mi][ni][r];
          float ex = fexp2(fmaf(-S2_F, a, cn));
          if (r & 1) nsb += ex; else nsa += ex;
          if (labv[mi][r >> 2][r & 3] == gcol) {  // rare: ~0.125/quadrant
            if (r & 1) nsb -= ex; else nsa -= ex; // exact cancel
            ps += fexp2(fmaf(S2_F, a, -pm));      // pe - lmax
          }
        }
      float ns = nsa + nsb;
      ps += __shfl_xor(ps, 32);
      ns += __shfl_xor(ns, 32);
      if (kg == 0) {
        colred[wr][col_local][0] = lmax;
        colred[wr][col_local][1] = ps;
        colred[wr][col_local][2] = ns;
      }
    }
    __syncthreads();  // colred ready; also drains next-B staging (vmcnt 0)
    if (tid < 128) {  // merge the two row-halves, write block partials
      float m0 = colred[0][tid][0], m1 = colred[1][tid][0];
      float M = fmaxf(m0, m1);
      float s0 = fexp2(m0 - M), s1 = fexp2(m1 - M);
      int gcol = cb * 128 + tid;
      wsM[rb * C_CLS + gcol] = M;
      wsP[rb * C_CLS + gcol] = fmaf(colred[0][tid][1], s0, colred[1][tid][1] * s1);
      wsN[rb * C_CLS + gcol] = fmaf(colred[0][tid][2], s0, colred[1][tid][2] * s1);
    }
    // no trailing barrier: colred is only rewritten after the NEXT iter's
    // post-GEMM barrier, which the merge threads also join.
  }
}

// Merged reduction: 256 blocks x 256 thr. Per block: 32 columns, 8 parts x
// 4 rb LDS merge (as before) + per-window label scan -> nvp partial. Then
// last-block-done (fence + ticket): block #255 computes global m, num_valid,
// and the log1p sums, writing the final scalar. Fence-based release/acquire
// handles cross-XCD visibility.
__global__ __launch_bounds__(256) void k_red(
    const float* __restrict__ wsM, const float* __restrict__ wsP,
    const float* __restrict__ wsN, const int* __restrict__ labels,
    float* __restrict__ Mcol, float* __restrict__ Pcol,
    float* __restrict__ Ncol, int* __restrict__ nvp,
    int* __restrict__ counter, float* __restrict__ out) {
  __shared__ float red[8][32][3];  // 3 KB
  __shared__ int fl[32];
  __shared__ int ticket;
  const int tid = threadIdx.x;
  const int col = tid & 31, part = tid >> 5;   // 8 parts x 4 rb each
  const int bx = blockIdx.x;
  const int j = bx * 32 + col;

  if (tid < 32) fl[tid] = 0;

  float m4[4];
  float M = -1e30f;
  #pragma unroll
  for (int r = 0; r < 4; ++r) {
    m4[r] = wsM[(part * 4 + r) * C_CLS + j];
    M = fmaxf(M, m4[r]);
  }
  float ps = 0.f, ns = 0.f;
  #pragma unroll
  for (int r = 0; r < 4; ++r) {
    float s = fexp2(m4[r] - M);
    ps = fmaf(wsP[(part * 4 + r) * C_CLS + j], s, ps);
    ns = fmaf(wsN[(part * 4 + r) * C_CLS + j], s, ns);
  }
  red[part][col][0] = M; red[part][col][1] = ps; red[part][col][2] = ns;
  __syncthreads();

  // Label-window scan: 4096 labels, int4-vectorized, 4 iters of 256 thr.
  #pragma unroll
  for (int it = 0; it < 4; ++it) {
    int4 lb = ((const int4*)labels)[it * 256 + tid];
    if ((lb.x >> 5) == bx) fl[lb.x & 31] = 1;
    if ((lb.y >> 5) == bx) fl[lb.y & 31] = 1;
    if ((lb.z >> 5) == bx) fl[lb.z & 31] = 1;
    if ((lb.w >> 5) == bx) fl[lb.w & 31] = 1;
  }

  if (part == 0) {
    float Mx = -1e30f;
    #pragma unroll
    for (int p = 0; p < 8; ++p) Mx = fmaxf(Mx, red[p][col][0]);
    float P = 0.f, Nn = 0.f;
    #pragma unroll
    for (int p = 0; p < 8; ++p) {
      float s = fexp2(red[p][col][0] - Mx);
      P = fmaf(red[p][col][1], s, P);
      Nn = fmaf(red[p][col][2], s, Nn);
    }
    Mcol[j] = Mx; Pcol[j] = P; Ncol[j] = Nn;
  }
  __syncthreads();
  if (tid < 64) {
    int f = (tid < 32) ? fl[tid] : 0;
    #pragma unroll
    for (int s = 32; s >= 1; s >>= 1) f += __shfl_xor(f, s);
    if (tid == 0) nvp[bx] = f;
  }

  // ---- last-block-done handoff ----
  __threadfence();          // release this block's Mcol/Pcol/Ncol/nvp writes
  __syncthreads();
  if (tid == 0) ticket = atomicAdd(counter, 1);
  __syncthreads();
  if (ticket != 255) return;
  __threadfence();          // acquire: invalidate stale caches before reads

  // ---- final phase: 256 threads, 4 waves, one CU ----
  __shared__ float sA[4], sB[4];
  __shared__ int sI[4];
  const int wvf = tid >> 6, lane = tid & 63;

  float Mv[32], Pv[32], Nv[32];
  float gm = -1e30f;
  #pragma unroll
  for (int k = 0; k < 32; ++k) {
    int i = k * 256 + tid;
    Mv[k] = Mcol[i]; Pv[k] = Pcol[i]; Nv[k] = Ncol[i];
    gm = fmaxf(gm, Mv[k]);
  }
  int nv = nvp[tid];
  #pragma unroll
  for (int s = 32; s >= 1; s >>= 1) {
    gm = fmaxf(gm, __shfl_xor(gm, s));
    nv += __shfl_xor(nv, s);
  }
  if (lane == 0) { sA[wvf] = gm; sI[wvf] = nv; }
  __syncthreads();
  if (tid == 0) {
    float mm = fmaxf(fmaxf(sA[0], sA[1]), fmaxf(sA[2], sA[3]));
    sA[0] = mm; sI[0] = sI[0] + sI[1] + sI[2] + sI[3];
  }
  __syncthreads();
  const float m = sA[0];          // log2 domain
  const int num_valid = sI[0];
  __syncthreads();
  float pt = 0.f, nt = 0.f;
  #pragma unroll
  for (int k = 0; k < 32; ++k) {
    float s = fexp2(Mv[k] - m);
    float xp = Pv[k] * s;
    float xn = Nv[k] * s;
    // log1p(x) = x to f32 precision when x < 1e-7 (most columns are
    // astronomically below the global max -> wave-uniform skip of ocml).
    pt += (xp > 1e-7f) ? log1pf(xp) : xp;
    nt += (xn > 1e-7f) ? log1pf(xn) : xn;
  }
  #pragma unroll
  for (int s = 32; s >= 1; s >>= 1) {
    pt += __shfl_xor(pt, s);
    nt += __shfl_xor(nt, s);
  }
  if (lane == 0) { sA[wvf] = pt; sB[wvf] = nt; }
  __syncthreads();
  if (tid == 0) {
    float sp = sA[0] + sA[1] + sA[2] + sA[3];
    float sn = sB[0] + sB[1] + sB[2] + sB[3];
    const float mn = m * LN2_F;   // back to natural-log domain
    out[0] = (sp + (float)C_CLS * mn) / (float)num_valid
           + (sn + (float)C_CLS * mn) / (float)C_CLS;
  }
}

extern "C" void kernel_launch(void* const* d_in, const int* in_sizes, int n_in,
                              void* d_out, int out_size, void* d_ws, size_t ws_size,
                              hipStream_t stream) {
  const float* emb    = (const float*)d_in[0];
  const int*   labels = (const int*)d_in[1];
  const float* mp     = (const float*)d_in[2];
  const float* lvp    = (const float*)d_in[3];
  float* out = (float*)d_out;

  char* ws = (char*)d_ws;
  __bf16* wsA   = (__bf16*)ws;                            // 4096*128*2 = 1 MB
  __bf16* wsB   = (__bf16*)(ws + (1u << 20));             // 8192*128*2 = 2 MB
  float* constv = (float*)(ws + 3u * (1u << 20));         // 32 KB
  float* wsM    = (float*)(ws + 3u * (1u << 20) + (1u << 15));  // 32*8192*4 = 1 MB
  float* wsP    = wsM + 32 * C_CLS;                       // 1 MB
  float* wsN    = wsP + 32 * C_CLS;                       // 1 MB
  float* Mcol   = wsN + 32 * C_CLS;                       // 32 KB
  float* Pcol   = Mcol + C_CLS;                           // 32 KB
  float* Ncol   = Pcol + C_CLS;                           // 32 KB
  int*   nvp    = (int*)(Ncol + C_CLS);                   // 1 KB
  int*   counter = nvp + 256;                             // 4 B

  // 12288 rows / 4 rows-per-wave / 4 waves-per-block = 768 blocks
  hipLaunchKernelGGL(k_prep, dim3(768), dim3(256), 0, stream,
                     emb, mp, lvp, wsA, wsB, constv, counter);
  // 32 rb x 16 cbg (4 cb tiles per block) = 512 blocks, 2/CU, one full round
  hipLaunchKernelGGL(k_main, dim3(32 * (C_CLS / 128 / NCB)), dim3(256), 0, stream,
                     wsA, wsB, constv, labels, wsM, wsP, wsN);
  hipLaunchKernelGGL(k_red, dim3(256), dim3(256), 0, stream,
                     wsM, wsP, wsN, labels, Mcol, Pcol, Ncol, nvp, counter, out);
}

// Round 5
// 89.777 us; speedup vs baseline: 1.2761x; 1.2761x over previous
//
#include <hip/hip_runtime.h>
#include <hip/hip_bf16.h>
#include <math.h>

// ProxyMLS: score = -0.5*(e2@iv^T - 2*e@(mu*iv)^T + const_j)
// pos_e = -32*(score-0.1) = 16*raw + (16*const_j + 3.2);  neg_e = 6.4 - pos_e
// R15: bisect of R14's +15.8us regression. R14 bundled (a) epilogue diet and
// (b) k_red1+k_fin merge via threadfence/atomic ticket. The merge's device-
// scope fences (buffer_wbl2 on dirty poison-filled L2s x256 blocks) +
// serialized cross-XCD atomics are the prime suspect. R15 = R13 structure
// (split k_red1/k_fin, NO fences/atomics) + the low-risk R14 pieces:
// k_main epilogue diet (raw-acc v_max3 tree, single-FMA neg-exp arg) and
// k_fin log1p fast path (x<1e-7 -> x).
//
// Scale constants: S2 = 16*log2e, B2 = 3.2*log2e, NEGC2 = 6.4*log2e.
// k_fin converts back with m_natural = m' * ln2.

#define N_EMB 4096
#define C_CLS 8192
#define D_DIM 64
#define K_DIM 128   // concat [e^2 | e] x [iv | -2*mu*iv]
#define NCB 4       // cb tiles per k_main block

#define S2_F    23.083120654223414f   // 16  * log2(e)
#define B2_F     4.616624130844683f   // 3.2 * log2(e)
#define NEGC2_F  9.233248261689366f   // 6.4 * log2(e)
#define LN2_F    0.6931471805599453f

typedef __attribute__((ext_vector_type(8))) __bf16 bf16x8;
typedef __attribute__((ext_vector_type(4))) __bf16 bf16x4;
typedef __attribute__((ext_vector_type(16))) float f32x16;
typedef __attribute__((ext_vector_type(4))) int i32x4;

__device__ __forceinline__ void async_ld16(void* lds, const void* g) {
  __builtin_amdgcn_global_load_lds(
      (__attribute__((address_space(1))) void*)g,
      (__attribute__((address_space(3))) void*)lds, 16, 0, 0);
}

// Raw hardware exp2 (v_exp_f32). exp2f would call __ocml_exp2_f32
// (subnormal fixup, ~6-10 instrs) -- measured +3us in R12.
__device__ __forceinline__ float fexp2(float x) {
  float r;
  asm("v_exp_f32 %0, %1" : "=v"(r) : "v"(x));
  return r;
}

// 3-input max in one instruction (gfx9+).
__device__ __forceinline__ float fmax3(float a, float b, float c) {
  float r;
  asm("v_max3_f32 %0, %1, %2, %3" : "=v"(r) : "v"(a), "v"(b), "v"(c));
  return r;
}

// Vectorized prep: wave handles 4 rows; lane = (sub=lane>>4 row, q=lane&15
// covering d = q*4..q*4+3 via float4). A=[e^2|e], B=[iv|-2*mu*iv],
// const_j = sum_d(mu^2*iv + logvar) via 16-lane xor-shuffle reduce.
__global__ void k_prep(const float* __restrict__ emb,
                       const float* __restrict__ mp,
                       const float* __restrict__ lvp,
                       __bf16* __restrict__ wsA,
                       __bf16* __restrict__ wsB,
                       float* __restrict__ constv) {
  const int wave = (int)((blockIdx.x * blockDim.x + threadIdx.x) >> 6);
  const int lane = threadIdx.x & 63;
  const int sub = lane >> 4, q = lane & 15;
  const int row = wave * 4 + sub;   // 12288 rows total
  if (row < N_EMB) {
    float4 e4 = *(const float4*)&emb[row * D_DIM + q * 4];
    bf16x4 sq = {(__bf16)(e4.x * e4.x), (__bf16)(e4.y * e4.y),
                 (__bf16)(e4.z * e4.z), (__bf16)(e4.w * e4.w)};
    bf16x4 ev = {(__bf16)e4.x, (__bf16)e4.y, (__bf16)e4.z, (__bf16)e4.w};
    *(bf16x4*)&wsA[row * K_DIM + q * 4] = sq;
    *(bf16x4*)&wsA[row * K_DIM + D_DIM + q * 4] = ev;
  } else {
    const int j = row - N_EMB;
    float4 mu4 = *(const float4*)&mp[j * D_DIM + q * 4];
    float4 lv4 = *(const float4*)&lvp[j * D_DIM + q * 4];
    float iv0 = __expf(-lv4.x), iv1 = __expf(-lv4.y);
    float iv2 = __expf(-lv4.z), iv3 = __expf(-lv4.w);
    bf16x4 ivv = {(__bf16)iv0, (__bf16)iv1, (__bf16)iv2, (__bf16)iv3};
    bf16x4 mv = {(__bf16)(-2.0f * mu4.x * iv0), (__bf16)(-2.0f * mu4.y * iv1),
                 (__bf16)(-2.0f * mu4.z * iv2), (__bf16)(-2.0f * mu4.w * iv3)};
    *(bf16x4*)&wsB[j * K_DIM + q * 4] = ivv;
    *(bf16x4*)&wsB[j * K_DIM + D_DIM + q * 4] = mv;
    float t = fmaf(mu4.x * mu4.x, iv0, lv4.x)
            + fmaf(mu4.y * mu4.y, iv1, lv4.y)
            + fmaf(mu4.z * mu4.z, iv2, lv4.z)
            + fmaf(mu4.w * mu4.w, iv3, lv4.w);
    #pragma unroll
    for (int s = 8; s >= 1; s >>= 1) t += __shfl_xor(t, s);  // within 16-group
    if (q == 0) constv[j] = t;
  }
}

// 128x(4x128) per block: A tile staged once, 4 B tiles staged sequentially
// (next tile's async loads fly under the current epilogue). bf16 32x32x16
// MFMA GEMM (K=128) + fused per-column online max / masked exp-sums (log2
// domain). Partials -> ws[rb][gcol].
//
// LDS tile layout: 128 rows x 16 chunks (16 B each), row stride 256 B.
// Slot (r, cs) holds GLOBAL chunk (r, cs ^ (r & 15)). Reader of chunk c of
// row r loads slot c ^ (r & 15) -> conflict-free (m136).
__global__ __launch_bounds__(256, 2) void k_main(
    const __bf16* __restrict__ wsA, const __bf16* __restrict__ wsB,
    const float* __restrict__ constv, const int* __restrict__ labels,
    float* __restrict__ wsM, float* __restrict__ wsP, float* __restrict__ wsN) {
  __shared__ __align__(16) char As[32768];  // 32 KB
  __shared__ __align__(16) char Bs[32768];  // 32 KB
  __shared__ float colred[2][128][3];       // 3 KB  (68.4 KB total -> 2 blk/CU)

  const int tid = threadIdx.x;
  const int rb  = blockIdx.x & 31;   // row block (N/128 = 32)
  const int cbg = blockIdx.x >> 5;   // col group (16 groups of NCB tiles)

  const char* Ag = (const char*)(wsA + (size_t)rb * 128 * K_DIM);
  const char* Bgb = (const char*)(wsB + (size_t)(cbg * NCB) * 128 * K_DIM);
  #pragma unroll
  for (int it = 0; it < 8; ++it) {
    int L = it * 256 + tid;
    int r = L >> 4, cs = L & 15;
    int goff = r * 256 + ((cs ^ (r & 15)) << 4);
    async_ld16(As + L * 16, Ag + goff);
  }
  #pragma unroll
  for (int it = 0; it < 8; ++it) {
    int L = it * 256 + tid;
    int r = L >> 4, cs = L & 15;
    int goff = r * 256 + ((cs ^ (r & 15)) << 4);
    async_ld16(Bs + L * 16, Bgb + goff);
  }

  const int wv = tid >> 6, lane = tid & 63;
  const int wr = wv >> 1, wc = wv & 1;   // 2x2 wave grid, 64x64 per wave
  const int l31 = lane & 31, kg = lane >> 5;  // A/B frag: row=l31, k=kg*8+j
  const int l15 = lane & 15;

  // Epilogue inputs straight to registers; latency hides under staging.
  // Label rows for C/D layout: base = wr*64 + mi*32 + 4*kg + 8*g.
  i32x4 labv[2][4];
  #pragma unroll
  for (int mi = 0; mi < 2; ++mi)
    #pragma unroll
    for (int g = 0; g < 4; ++g)
      labv[mi][g] = *(const i32x4*)&labels[rb * 128 + wr * 64 + mi * 32 +
                                           4 * kg + 8 * g];
  float cvv[NCB][2];
  #pragma unroll
  for (int cbi = 0; cbi < NCB; ++cbi)
    #pragma unroll
    for (int ni = 0; ni < 2; ++ni)
      cvv[cbi][ni] = constv[(cbg * NCB + cbi) * 128 + wc * 64 + ni * 32 + l31];

  __syncthreads();  // drains vmcnt: As + Bs(tile 0) ready

  #pragma unroll
  for (int cbi = 0; cbi < NCB; ++cbi) {
    const int cb = cbg * NCB + cbi;

    f32x16 acc[2][2];
    #pragma unroll
    for (int mi = 0; mi < 2; ++mi)
      #pragma unroll
      for (int ni = 0; ni < 2; ++ni)
        #pragma unroll
        for (int r = 0; r < 16; ++r) acc[mi][ni][r] = 0.f;

    #pragma unroll
    for (int kk = 0; kk < 8; ++kk) {       // K = 8 steps of 16
      const int c = kk * 2 + kg;           // wanted 16B K-chunk
      const int cofs = (c ^ l15) << 4;     // swizzled byte offset (row&15==l15)
      bf16x8 af[2], bfr[2];
      #pragma unroll
      for (int mi = 0; mi < 2; ++mi)
        af[mi] = *(const bf16x8*)(As + (wr * 64 + mi * 32 + l31) * 256 + cofs);
      #pragma unroll
      for (int ni = 0; ni < 2; ++ni)
        bfr[ni] = *(const bf16x8*)(Bs + (wc * 64 + ni * 32 + l31) * 256 + cofs);
      #pragma unroll
      for (int mi = 0; mi < 2; ++mi)
        #pragma unroll
        for (int ni = 0; ni < 2; ++ni)
          acc[mi][ni] = __builtin_amdgcn_mfma_f32_32x32x16_bf16(
              af[mi], bfr[ni], acc[mi][ni], 0, 0, 0);
    }

    __syncthreads();  // all waves done reading Bs

    if (cbi + 1 < NCB) {  // stage next B tile; flies under the epilogue
      const char* Bg = Bgb + (size_t)(cbi + 1) * 32768;
      #pragma unroll
      for (int it = 0; it < 8; ++it) {
        int L = it * 256 + tid;
        int r = L >> 4, cs = L & 15;
        int goff = r * 256 + ((cs ^ (r & 15)) << 4);
        async_ld16(Bs + L * 16, Bg + goff);
      }
    }

    // Epilogue. C/D layout (32x32, m74/m101): col = lane&31,
    // row = (reg&3) + 8*(reg>>2) + 4*kg.
    #pragma unroll
    for (int ni = 0; ni < 2; ++ni) {
      const int col_local = wc * 64 + ni * 32 + l31;
      const int gcol = cb * 128 + col_local;
      const float pcv = fmaf(S2_F, cvv[cbi][ni], B2_F);

      // Raw-acc max via v_max3 tree (pcv const per column, S2 > 0).
      #define AV(k) acc[(k) >> 4][ni][(k) & 15]
      float t0 = fmax3(AV(0), AV(1), AV(2));
      float t1 = fmax3(AV(3), AV(4), AV(5));
      float t2 = fmax3(AV(6), AV(7), AV(8));
      float t3 = fmax3(AV(9), AV(10), AV(11));
      float t4 = fmax3(AV(12), AV(13), AV(14));
      float t5 = fmax3(AV(15), AV(16), AV(17));
      float t6 = fmax3(AV(18), AV(19), AV(20));
      float t7 = fmax3(AV(21), AV(22), AV(23));
      float t8 = fmax3(AV(24), AV(25), AV(26));
      float t9 = fmax3(AV(27), AV(28), AV(29));
      float ta = fmaxf(AV(30), AV(31));
      #undef AV
      float u0 = fmax3(t0, t1, t2);
      float u1 = fmax3(t3, t4, t5);
      float u2 = fmax3(t6, t7, t8);
      float u3 = fmax3(t9, ta, u0);
      float rm = fmax3(u1, u2, u3);
      rm = fmaxf(rm, __shfl_xor(rm, 32));   // other kg half = other rows

      const float pm = S2_F * rm;
      const float lmax = pm + pcv;          // pe-domain column max
      const float cn = NEGC2_F - pm - 2.0f * pcv;  // neg arg = fma(-S2,a,cn)

      float nsa = 0.f, nsb = 0.f, ps = 0.f;
      #pragma unroll
      for (int mi = 0; mi < 2; ++mi)
        #pragma unroll
        for (int r = 0; r < 16; ++r) {
          float a = acc[mi][ni][r];
          float ex = fexp2(fmaf(-S2_F, a, cn));
          if (r & 1) nsb += ex; else nsa += ex;
          if (labv[mi][r >> 2][r & 3] == gcol) {  // rare: ~0.125/quadrant
            if (r & 1) nsb -= ex; else nsa -= ex; // exact cancel
            ps += fexp2(fmaf(S2_F, a, -pm));      // pe - lmax
          }
        }
      float ns = nsa + nsb;
      ps += __shfl_xor(ps, 32);
      ns += __shfl_xor(ns, 32);
      if (kg == 0) {
        colred[wr][col_local][0] = lmax;
        colred[wr][col_local][1] = ps;
        colred[wr][col_local][2] = ns;
      }
    }
    __syncthreads();  // colred ready; also drains next-B staging (vmcnt 0)
    if (tid < 128) {  // merge the two row-halves, write block partials
      float m0 = colred[0][tid][0], m1 = colred[1][tid][0];
      float M = fmaxf(m0, m1);
      float s0 = fexp2(m0 - M), s1 = fexp2(m1 - M);
      int gcol = cb * 128 + tid;
      wsM[rb * C_CLS + gcol] = M;
      wsP[rb * C_CLS + gcol] = fmaf(colred[0][tid][1], s0, colred[1][tid][1] * s1);
      wsN[rb * C_CLS + gcol] = fmaf(colred[0][tid][2], s0, colred[1][tid][2] * s1);
    }
    // no trailing barrier: colred is only rewritten after the NEXT iter's
    // post-GEMM barrier, which the merge threads also join.
  }
}

// Reduction stage 1: 256 blocks x 256 thr (one block per CU). Block =
// 32 columns; part=tid>>5 covers 4 of 32 row-blocks. LDS merge across
// 8 parts. Also: each block scans the 4096 labels against its 32-col
// window and emits a num_valid partial. No fences/atomics.
__global__ __launch_bounds__(256) void k_red1(
    const float* __restrict__ wsM, const float* __restrict__ wsP,
    const float* __restrict__ wsN, const int* __restrict__ labels,
    float* __restrict__ Mcol, float* __restrict__ Pcol,
    float* __restrict__ Ncol, int* __restrict__ nvp) {
  __shared__ float red[8][32][3];  // 3 KB
  __shared__ int fl[32];
  const int tid = threadIdx.x;
  const int col = tid & 31, part = tid >> 5;   // 8 parts x 4 rb each
  const int bx = blockIdx.x;
  const int j = bx * 32 + col;

  if (tid < 32) fl[tid] = 0;

  float m4[4];
  float M = -1e30f;
  #pragma unroll
  for (int r = 0; r < 4; ++r) {
    m4[r] = wsM[(part * 4 + r) * C_CLS + j];
    M = fmaxf(M, m4[r]);
  }
  float ps = 0.f, ns = 0.f;
  #pragma unroll
  for (int r = 0; r < 4; ++r) {
    float s = fexp2(m4[r] - M);
    ps = fmaf(wsP[(part * 4 + r) * C_CLS + j], s, ps);
    ns = fmaf(wsN[(part * 4 + r) * C_CLS + j], s, ns);
  }
  red[part][col][0] = M; red[part][col][1] = ps; red[part][col][2] = ns;
  __syncthreads();

  // Label-window scan: 4096 labels, int4-vectorized, 4 iters of 256 thr.
  #pragma unroll
  for (int it = 0; it < 4; ++it) {
    int4 lb = ((const int4*)labels)[it * 256 + tid];
    if ((lb.x >> 5) == bx) fl[lb.x & 31] = 1;
    if ((lb.y >> 5) == bx) fl[lb.y & 31] = 1;
    if ((lb.z >> 5) == bx) fl[lb.z & 31] = 1;
    if ((lb.w >> 5) == bx) fl[lb.w & 31] = 1;
  }

  if (part == 0) {
    float Mx = -1e30f;
    #pragma unroll
    for (int p = 0; p < 8; ++p) Mx = fmaxf(Mx, red[p][col][0]);
    float P = 0.f, Nn = 0.f;
    #pragma unroll
    for (int p = 0; p < 8; ++p) {
      float s = fexp2(red[p][col][0] - Mx);
      P = fmaf(red[p][col][1], s, P);
      Nn = fmaf(red[p][col][2], s, Nn);
    }
    Mcol[j] = Mx; Pcol[j] = P; Ncol[j] = Nn;
  }
  __syncthreads();
  if (tid < 64) {
    int f = (tid < 32) ? fl[tid] : 0;
    #pragma unroll
    for (int s = 32; s >= 1; s >>= 1) f += __shfl_xor(f, s);
    if (tid == 0) nvp[bx] = f;
  }
}

// Final: single block x 1024 threads — global m, num_valid sum, log1p sums.
// All global loads issued at the top to hide latency. log1p fast path:
// x < 1e-7 -> log1p(x) = x to f32 precision (wave-uniformly skips ocml for
// the vast majority of columns, which sit far below the global max).
__global__ __launch_bounds__(1024) void k_fin(
    const float* __restrict__ Mcol, const float* __restrict__ Pcol,
    const float* __restrict__ Ncol, const int* __restrict__ nvp,
    float* __restrict__ out) {
  __shared__ float sA[16], sB[16];
  __shared__ int sI[16];
  const int tid = threadIdx.x;
  const int wv = tid >> 6, lane = tid & 63;

  float colMv[8], colPv[8], colNv[8];
  #pragma unroll
  for (int k = 0; k < 8; ++k) {
    int i = k * 1024 + tid;
    colMv[k] = Mcol[i]; colPv[k] = Pcol[i]; colNv[k] = Ncol[i];
  }
  int nv = (tid < 256) ? nvp[tid] : 0;

  float gm = -1e30f;
  #pragma unroll
  for (int k = 0; k < 8; ++k) gm = fmaxf(gm, colMv[k]);
  #pragma unroll
  for (int s = 32; s >= 1; s >>= 1) {
    gm = fmaxf(gm, __shfl_xor(gm, s));
    nv += __shfl_xor(nv, s);
  }
  if (lane == 0) { sA[wv] = gm; sI[wv] = nv; }
  __syncthreads();
  if (tid == 0) {
    float mm = -1e30f; int n = 0;
    #pragma unroll
    for (int k = 0; k < 16; ++k) { mm = fmaxf(mm, sA[k]); n += sI[k]; }
    sA[0] = mm; sI[0] = n;
  }
  __syncthreads();
  const float m = sA[0];          // log2 domain
  const int num_valid = sI[0];
  __syncthreads();
  float pt = 0.f, nt = 0.f;
  #pragma unroll
  for (int k = 0; k < 8; ++k) {
    float s = fexp2(colMv[k] - m);
    float xp = colPv[k] * s;
    float xn = colNv[k] * s;
    pt += (xp > 1e-7f) ? log1pf(xp) : xp;
    nt += (xn > 1e-7f) ? log1pf(xn) : xn;
  }
  #pragma unroll
  for (int s = 32; s >= 1; s >>= 1) {
    pt += __shfl_xor(pt, s);
    nt += __shfl_xor(nt, s);
  }
  if (lane == 0) { sA[wv] = pt; sB[wv] = nt; }
  __syncthreads();
  if (tid == 0) {
    float sp = 0.f, sn = 0.f;
    #pragma unroll
    for (int k = 0; k < 16; ++k) { sp += sA[k]; sn += sB[k]; }
    const float mn = m * LN2_F;   // back to natural-log domain
    out[0] = (sp + (float)C_CLS * mn) / (float)num_valid
           + (sn + (float)C_CLS * mn) / (float)C_CLS;
  }
}

extern "C" void kernel_launch(void* const* d_in, const int* in_sizes, int n_in,
                              void* d_out, int out_size, void* d_ws, size_t ws_size,
                              hipStream_t stream) {
  const float* emb    = (const float*)d_in[0];
  const int*   labels = (const int*)d_in[1];
  const float* mp     = (const float*)d_in[2];
  const float* lvp    = (const float*)d_in[3];
  float* out = (float*)d_out;

  char* ws = (char*)d_ws;
  __bf16* wsA   = (__bf16*)ws;                            // 4096*128*2 = 1 MB
  __bf16* wsB   = (__bf16*)(ws + (1u << 20));             // 8192*128*2 = 2 MB
  float* constv = (float*)(ws + 3u * (1u << 20));         // 32 KB
  float* wsM    = (float*)(ws + 3u * (1u << 20) + (1u << 15));  // 32*8192*4 = 1 MB
  float* wsP    = wsM + 32 * C_CLS;                       // 1 MB
  float* wsN    = wsP + 32 * C_CLS;                       // 1 MB
  float* Mcol   = wsN + 32 * C_CLS;                       // 32 KB
  float* Pcol   = Mcol + C_CLS;                           // 32 KB
  float* Ncol   = Pcol + C_CLS;                           // 32 KB
  int*   nvp    = (int*)(Ncol + C_CLS);                   // 1 KB

  // 12288 rows / 4 rows-per-wave / 4 waves-per-block = 768 blocks
  hipLaunchKernelGGL(k_prep, dim3(768), dim3(256), 0, stream,
                     emb, mp, lvp, wsA, wsB, constv);
  // 32 rb x 16 cbg (4 cb tiles per block) = 512 blocks, 2/CU, one full round
  hipLaunchKernelGGL(k_main, dim3(32 * (C_CLS / 128 / NCB)), dim3(256), 0, stream,
                     wsA, wsB, constv, labels, wsM, wsP, wsN);
  hipLaunchKernelGGL(k_red1, dim3(256), dim3(256), 0, stream,
                     wsM, wsP, wsN, labels, Mcol, Pcol, Ncol, nvp);
  hipLaunchKernelGGL(k_fin, dim3(1), dim3(1024), 0, stream,
                     Mcol, Pcol, Ncol, nvp, out);
}